// Round 1
// baseline (270.004 us; speedup 1.0000x reference)
//
#include <hip/hip_runtime.h>

// BoxFilter: 21x21 all-ones box filter, circular padding, x: f32[8,1,2048,2048].
// Separable: row sums then column sums, fused in one kernel via LDS tiles.

#define HH 2048
#define WW 2048
#define RAD 10
#define DIAM 21
#define TH 64
#define TW 64
#define SIN_H (TH + 2 * RAD)      // 84
#define SIN_W (TW + 2 * RAD)      // 84
#define SIN_STRIDE (SIN_W + 1)    // 85 (odd -> spreads banks)
#define RS_STRIDE (TW + 1)        // 65 (odd -> 2-way max, free)

__global__ __launch_bounds__(256) void box_filter_kernel(
    const float* __restrict__ x, float* __restrict__ out) {
  __shared__ float sIn[SIN_H * SIN_STRIDE];
  __shared__ float sRS[SIN_H * RS_STRIDE];

  const int n = blockIdx.z;
  const int tile_h0 = blockIdx.y * TH;
  const int tile_w0 = blockIdx.x * TW;
  const float* __restrict__ xp = x + (size_t)n * HH * WW;
  float* __restrict__ op = out + (size_t)n * HH * WW;
  const int tid = threadIdx.x;

  // ---- Phase 1: stage 84x84 input tile (+halo, circular wrap) into LDS ----
  for (int idx = tid; idx < SIN_H * SIN_W; idx += 256) {
    int i = idx / SIN_W;
    int j = idx - i * SIN_W;
    int gr = (tile_h0 + i - RAD) & (HH - 1);  // two's-complement AND handles <0
    int gc = (tile_w0 + j - RAD) & (WW - 1);
    sIn[i * SIN_STRIDE + j] = xp[(size_t)gr * WW + gc];
  }
  __syncthreads();

  // ---- Phase 2: row sums. 84 rows x 4 chunks of 16 cols = 336 tasks ----
  for (int t = tid; t < SIN_H * 4; t += 256) {
    int i = t >> 2;
    int jg = (t & 3) * 16;
    const float* row = &sIn[i * SIN_STRIDE];
    float* rsrow = &sRS[i * RS_STRIDE];
    float sum = 0.f;
#pragma unroll
    for (int k = 0; k < DIAM; ++k) sum += row[jg + k];
    rsrow[jg] = sum;
#pragma unroll
    for (int j = 1; j < 16; ++j) {
      sum += row[jg + j + DIAM - 1] - row[jg + j - 1];
      rsrow[jg + j] = sum;
    }
  }
  __syncthreads();

  // ---- Phase 3: column sums + store. j = tid&63 (coalesced), 16 rows/thread ----
  {
    int j = tid & 63;
    int i0 = (tid >> 6) * 16;
    float sum = 0.f;
#pragma unroll
    for (int k = 0; k < DIAM; ++k) sum += sRS[(i0 + k) * RS_STRIDE + j];
    const int gc = tile_w0 + j;
    const int gr = tile_h0 + i0;
    op[(size_t)gr * WW + gc] = sum;
#pragma unroll
    for (int i = 1; i < 16; ++i) {
      sum += sRS[(i0 + i + DIAM - 1) * RS_STRIDE + j] -
             sRS[(i0 + i - 1) * RS_STRIDE + j];
      op[(size_t)(gr + i) * WW + gc] = sum;
    }
  }
}

extern "C" void kernel_launch(void* const* d_in, const int* in_sizes, int n_in,
                              void* d_out, int out_size, void* d_ws, size_t ws_size,
                              hipStream_t stream) {
  const float* x = (const float*)d_in[0];
  // d_in[1] is the all-ones 21x21 kernel; the Angle==0 path makes it constant.
  float* out = (float*)d_out;
  dim3 grid(WW / TW, HH / TH, 8);
  dim3 block(256);
  hipLaunchKernelGGL(box_filter_kernel, grid, block, 0, stream, x, out);
}

// Round 2
// 260.632 us; speedup vs baseline: 1.0360x; 1.0360x over previous
//
#include <hip/hip_runtime.h>

// BoxFilter: 21x21 all-ones box, circular pad, x: f32[8,1,2048,2048].
// v2: vertical sliding sums global->regs (coalesced), colsums in LDS,
// one barrier, horizontal sliding sums -> float4 stores.

#define HH 2048
#define WW 2048
#define RAD 10
#define DIAM 21
#define TH 64
#define TW 64
#define CS_W (TW + 2 * RAD)    // 84 colsum columns
#define CS_STRIDE (CS_W + 1)   // 85 (odd -> <=2-way bank aliasing, free)

__global__ __launch_bounds__(256) void box_filter_v2(
    const float* __restrict__ x, float* __restrict__ out) {
  __shared__ float sCS[TH * CS_STRIDE];  // colsum[r][c], r=output row 0..63

  const int n = blockIdx.z;
  const int h0 = blockIdx.y * TH;
  const int w0 = blockIdx.x * TW;
  const float* __restrict__ xp = x + (size_t)n * HH * WW;
  float* __restrict__ op = out + (size_t)n * HH * WW;
  const int tid = threadIdx.x;

  // ---- Phase 1: vertical sliding sums. 84 cols x 4 row-groups = 336 tasks.
  // Each task: read 36 rows of one column (coalesced across lanes), slide a
  // 21-tap running sum down 16 output rows, write colsums to LDS.
  for (int t = tid; t < CS_W * 4; t += 256) {
    int c = t % CS_W;                    // 0..83
    int g = t / CS_W;                    // 0..3
    int gc = (w0 - RAD + c) & (WW - 1);  // circular in W
    int rbase = h0 + 16 * g - RAD;
    float v[36];
#pragma unroll
    for (int k = 0; k < 36; ++k)
      v[k] = xp[(size_t)((rbase + k) & (HH - 1)) * WW + gc];  // circular in H
    float s = 0.f;
#pragma unroll
    for (int k = 0; k < DIAM; ++k) s += v[k];
    sCS[(16 * g) * CS_STRIDE + c] = s;
#pragma unroll
    for (int i = 1; i < 16; ++i) {
      s += v[i + DIAM - 1] - v[i - 1];
      sCS[(16 * g + i) * CS_STRIDE + c] = s;
    }
  }
  __syncthreads();

  // ---- Phase 2: horizontal sliding sums. thread -> (row r, 16-col chunk cg).
  {
    int r = tid >> 2;
    int cg = tid & 3;
    const float* csrow = &sCS[r * CS_STRIDE + cg * 16];
    float w[36];
#pragma unroll
    for (int k = 0; k < 36; ++k) w[k] = csrow[k];
    float o[16];
    float s = 0.f;
#pragma unroll
    for (int k = 0; k < DIAM; ++k) s += w[k];
    o[0] = s;
#pragma unroll
    for (int j = 1; j < 16; ++j) {
      s += w[j + DIAM - 1] - w[j - 1];
      o[j] = s;
    }
    float4* dst = (float4*)&op[(size_t)(h0 + r) * WW + w0 + cg * 16];
#pragma unroll
    for (int q = 0; q < 4; ++q)
      dst[q] = make_float4(o[4 * q], o[4 * q + 1], o[4 * q + 2], o[4 * q + 3]);
  }
}

extern "C" void kernel_launch(void* const* d_in, const int* in_sizes, int n_in,
                              void* d_out, int out_size, void* d_ws, size_t ws_size,
                              hipStream_t stream) {
  const float* x = (const float*)d_in[0];
  float* out = (float*)d_out;
  dim3 grid(WW / TW, HH / TH, 8);
  dim3 block(256);
  hipLaunchKernelGGL(box_filter_v2, grid, block, 0, stream, x, out);
}